// Round 12
// baseline (234.790 us; speedup 1.0000x reference)
//
#include <hip/hip_runtime.h>

#define N_NODES 50000
#define N_EDGES 800000
#define F_IN    128
#define HID     32
#define HEADS   4
#define OUT_C   16

#define NBKT 196      // buckets = dst>>8 ; 196*256 = 50176 >= N_NODES
#define CAP  5120     // per-bucket capacity; mean 4082
#define EPB  4096     // edges per bucketA block; 196 blocks cover 802816
#define NB64 782      // ceil(N_NODES/64)

// bf16 helpers (RNE)
__device__ __forceinline__ unsigned short f2bf(float f) {
    unsigned int u = __float_as_uint(f);
    u += 0x7FFFu + ((u >> 16) & 1u);
    return (unsigned short)(u >> 16);
}
__device__ __forceinline__ float bf_lo(unsigned int u) { return __uint_as_float(u << 16); }
__device__ __forceinline__ float bf_hi(unsigned int u) { return __uint_as_float(u & 0xFFFF0000u); }

__device__ __forceinline__ float edge_w(float asv, float adv) {
    float v = asv + adv;
    v = (v > 0.f) ? v : 0.2f * v;        // leaky_relu(0.2)
    return __expf(v);                    // softmax shift-invariant; logits O(1)
}

// ================================================================ F1 = k_emb (h0 = x@Wemb+bemb) ∪ bucketA
__global__ __launch_bounds__(256) void k_F1(const float* __restrict__ x,
                                            const float* __restrict__ Wemb,
                                            const float* __restrict__ bemb,
                                            float* __restrict__ h0,
                                            const int* __restrict__ ei,
                                            int* __restrict__ gcnt,
                                            unsigned int* __restrict__ pairs,
                                            int* __restrict__ esrc) {
    __shared__ float xs[64][132];
    __shared__ float Wl[F_IN][HID];
    __shared__ float bl[HID];
    __shared__ int hist[NBKT];
    __shared__ int base[NBKT];
    int t = threadIdx.x;
    if (blockIdx.x < NB64) {
        int node0 = blockIdx.x * 64;
        if (t < HID) bl[t] = bemb[t];
        #pragma unroll
        for (int it = 0; it < 4; it++) {
            int idx = it * 256 + t;
            *(float4*)((float*)Wl + idx * 4) = *(const float4*)(Wemb + idx * 4);
        }
        #pragma unroll
        for (int it = 0; it < 8; it++) {
            int idx = it * 256 + t;
            int row = idx >> 5, c4 = idx & 31;
            float4 v = make_float4(0.f, 0.f, 0.f, 0.f);
            if (node0 + row < N_NODES) v = *(const float4*)(x + (size_t)(node0 + row) * F_IN + c4 * 4);
            *(float4*)&xs[row][c4 * 4] = v;
        }
        __syncthreads();
        int c = t & 7, g = t >> 3;
        float acc[2][4] = {};
        for (int k = 0; k < F_IN; k++) {
            float4 w4 = *(const float4*)&Wl[k][c * 4];
            #pragma unroll
            for (int n = 0; n < 2; n++) {
                float xv = xs[g * 2 + n][k];
                acc[n][0] += xv * w4.x; acc[n][1] += xv * w4.y;
                acc[n][2] += xv * w4.z; acc[n][3] += xv * w4.w;
            }
        }
        #pragma unroll
        for (int n = 0; n < 2; n++) {
            int node = node0 + g * 2 + n;
            if (node < N_NODES) {
                float4 o = make_float4(acc[n][0] + bl[c * 4], acc[n][1] + bl[c * 4 + 1],
                                       acc[n][2] + bl[c * 4 + 2], acc[n][3] + bl[c * 4 + 3]);
                *(float4*)(h0 + (size_t)node * HID + c * 4) = o;
            }
        }
    } else {
        if (blockIdx.x == NB64 && t < 64) esrc[N_EDGES + t] = 0;   // pad: gathers drop tail clamps (32-edge batches + prefetch)
        int e0 = (blockIdx.x - NB64) * EPB;
        for (int i = t; i < NBKT; i += 256) hist[i] = 0;
        __syncthreads();
        unsigned int p[16];
        int bb[16];
        #pragma unroll
        for (int i = 0; i < 16; i++) {
            int e = e0 + i * 256 + t;
            bb[i] = -1;
            if (e < N_EDGES) {
                int s = ei[e], d = ei[N_EDGES + e];
                p[i] = ((unsigned int)s << 8) | (unsigned int)(d & 255);
                bb[i] = d >> 8;
                atomicAdd(&hist[bb[i]], 1);
            }
        }
        __syncthreads();
        for (int i = t; i < NBKT; i += 256) {
            int c = hist[i];
            base[i] = i * CAP + (c ? atomicAdd(&gcnt[i], c) : 0);
            hist[i] = 0;
        }
        __syncthreads();
        #pragma unroll
        for (int i = 0; i < 16; i++) {
            if (bb[i] >= 0) {
                int off = atomicAdd(&hist[bb[i]], 1);
                pairs[base[bb[i]] + off] = p[i];
            }
        }
    }
}

// ================================================================ F2 = h1f (h1=h0@W1, bf16 + alpha dots) ∪ bucketB
__global__ __launch_bounds__(256) void k_F2(const float* __restrict__ h0,
                                            const float* __restrict__ W1,
                                            const float* __restrict__ a_src,
                                            const float* __restrict__ a_dst,
                                            unsigned short* __restrict__ h1,   // [N][128] bf16
                                            float* __restrict__ as, float* __restrict__ ad,  // [N][4]
                                            const unsigned int* __restrict__ pairs,
                                            const int* __restrict__ gcnt,
                                            int* __restrict__ rowptr,
                                            int* __restrict__ esrc) {
    __shared__ float xs[64][36];
    __shared__ float Wl[HID][128];
    __shared__ int cnt[256];
    __shared__ int cur[256];
    __shared__ int wsum[4];
    int t = threadIdx.x;
    if (blockIdx.x < NB64) {
        int node0 = blockIdx.x * 64;
        #pragma unroll
        for (int it = 0; it < 4; it++) {
            int idx = it * 256 + t;
            *(float4*)((float*)Wl + idx * 4) = *(const float4*)(W1 + idx * 4);
        }
        #pragma unroll
        for (int it = 0; it < 2; it++) {
            int idx = it * 256 + t;
            int row = idx >> 3, c4 = idx & 7;
            float4 v = make_float4(0.f, 0.f, 0.f, 0.f);
            if (node0 + row < N_NODES) v = *(const float4*)(h0 + (size_t)(node0 + row) * HID + c4 * 4);
            *(float4*)&xs[row][c4 * 4] = v;
        }
        __syncthreads();
        int c = t & 31, g = t >> 5;
        float acc[8][4] = {};
        for (int k = 0; k < HID; k++) {
            float4 w4 = *(const float4*)&Wl[k][c * 4];
            #pragma unroll
            for (int n = 0; n < 8; n++) {
                float xv = xs[g * 8 + n][k];
                acc[n][0] += xv * w4.x; acc[n][1] += xv * w4.y;
                acc[n][2] += xv * w4.z; acc[n][3] += xv * w4.w;
            }
        }
        float4 av = *(const float4*)(a_src + c * 4);
        float4 dv = *(const float4*)(a_dst + c * 4);
        float ps[8], pd[8];
        #pragma unroll
        for (int n = 0; n < 8; n++) {
            int node = node0 + g * 8 + n;
            if (node < N_NODES) {
                ushort4 o;
                o.x = f2bf(acc[n][0]); o.y = f2bf(acc[n][1]);
                o.z = f2bf(acc[n][2]); o.w = f2bf(acc[n][3]);
                *(ushort4*)(h1 + (size_t)node * 128 + c * 4) = o;
            }
            ps[n] = acc[n][0] * av.x + acc[n][1] * av.y + acc[n][2] * av.z + acc[n][3] * av.w;
            pd[n] = acc[n][0] * dv.x + acc[n][1] * dv.y + acc[n][2] * dv.z + acc[n][3] * dv.w;
        }
        #pragma unroll
        for (int mask = 1; mask <= 4; mask <<= 1) {
            #pragma unroll
            for (int n = 0; n < 8; n++) {
                ps[n] += __shfl_xor(ps[n], mask, 64);
                pd[n] += __shfl_xor(pd[n], mask, 64);
            }
        }
        if ((c & 7) == 0) {
            int hh = c >> 3;
            #pragma unroll
            for (int n = 0; n < 8; n++) {
                int node = node0 + g * 8 + n;
                if (node < N_NODES) { as[node * 4 + hh] = ps[n]; ad[node * 4 + hh] = pd[n]; }
            }
        }
    } else {
        int b = blockIdx.x - NB64;
        int lane = t & 63, wv = t >> 6;
        int v0 = (t < NBKT && t < b) ? gcnt[t] : 0;
        #pragma unroll
        for (int mask = 1; mask < 64; mask <<= 1) v0 += __shfl_xor(v0, mask, 64);
        if (lane == 0) wsum[wv] = v0;
        __syncthreads();
        int base = wsum[0] + wsum[1] + wsum[2] + wsum[3];
        int n0 = b << 8;
        int cntb = gcnt[b];
        int s0 = b * CAP;
        cnt[t] = 0;
        __syncthreads();
        for (int i = t; i < cntb; i += 256) atomicAdd(&cnt[pairs[s0 + i] & 255], 1);
        __syncthreads();
        int v = cnt[t], x = v;
        #pragma unroll
        for (int off = 1; off < 64; off <<= 1) { int y = __shfl_up(x, off, 64); if (lane >= off) x += y; }
        __syncthreads();
        if (lane == 63) wsum[wv] = x;
        __syncthreads();
        int add = 0;
        for (int j = 0; j < wv; j++) add += wsum[j];
        int excl = base + (x - v) + add;
        cur[t] = excl;
        if (n0 + t < N_NODES) rowptr[n0 + t] = excl;
        if (b == 0 && t == 0) rowptr[N_NODES] = N_EDGES;
        __syncthreads();
        for (int i = t; i < cntb; i += 256) {
            unsigned int p = pairs[s0 + i];
            int pos = atomicAdd(&cur[p & 255], 1);
            esrc[pos] = (int)(p >> 8);
        }
    }
}

// ================================================================ h2 = out1(bf16) @ W2 (bf16 out) + fused alpha2
__global__ __launch_bounds__(256) void k_h2f(const unsigned int* __restrict__ hin,  // [N][64] bf16x2
                                             const float* __restrict__ W2,
                                             const float* __restrict__ a_src,
                                             const float* __restrict__ a_dst,
                                             unsigned short* __restrict__ h2,       // [N][64] bf16
                                             float* __restrict__ as, float* __restrict__ ad) {
    __shared__ float xs[64][132];
    __shared__ float Wl[128][64];
    int t = threadIdx.x;
    int node0 = blockIdx.x * 64;
    #pragma unroll
    for (int it = 0; it < 8; it++) {
        int idx = it * 256 + t;
        *(float4*)((float*)Wl + idx * 4) = *(const float4*)(W2 + idx * 4);
    }
    #pragma unroll
    for (int it = 0; it < 8; it++) {
        int idx = it * 256 + t;
        int row = idx >> 5, c4 = idx & 31;
        float4 v = make_float4(0.f, 0.f, 0.f, 0.f);
        if (node0 + row < N_NODES) {
            uint2 u = *(const uint2*)(hin + (size_t)(node0 + row) * 64 + c4 * 2);
            v = make_float4(bf_lo(u.x), bf_hi(u.x), bf_lo(u.y), bf_hi(u.y));
        }
        *(float4*)&xs[row][c4 * 4] = v;
    }
    __syncthreads();
    int c = t & 15, g = t >> 4;
    float acc[4][4] = {};
    for (int k = 0; k < 128; k++) {
        float4 w4 = *(const float4*)&Wl[k][c * 4];
        #pragma unroll
        for (int n = 0; n < 4; n++) {
            float xv = xs[g * 4 + n][k];
            acc[n][0] += xv * w4.x; acc[n][1] += xv * w4.y;
            acc[n][2] += xv * w4.z; acc[n][3] += xv * w4.w;
        }
    }
    float4 av = *(const float4*)(a_src + c * 4);
    float4 dv = *(const float4*)(a_dst + c * 4);
    float ps[4], pd[4];
    #pragma unroll
    for (int n = 0; n < 4; n++) {
        int node = node0 + g * 4 + n;
        if (node < N_NODES) {
            ushort4 o;
            o.x = f2bf(acc[n][0]); o.y = f2bf(acc[n][1]);
            o.z = f2bf(acc[n][2]); o.w = f2bf(acc[n][3]);
            *(ushort4*)(h2 + (size_t)node * 64 + c * 4) = o;
        }
        ps[n] = acc[n][0] * av.x + acc[n][1] * av.y + acc[n][2] * av.z + acc[n][3] * av.w;
        pd[n] = acc[n][0] * dv.x + acc[n][1] * dv.y + acc[n][2] * dv.z + acc[n][3] * dv.w;
    }
    #pragma unroll
    for (int mask = 1; mask <= 2; mask <<= 1) {
        #pragma unroll
        for (int n = 0; n < 4; n++) {
            ps[n] += __shfl_xor(ps[n], mask, 64);
            pd[n] += __shfl_xor(pd[n], mask, 64);
        }
    }
    if ((c & 3) == 0) {
        int hh = c >> 2;
        #pragma unroll
        for (int n = 0; n < 4; n++) {
            int node = node0 + g * 4 + n;
            if (node < N_NODES) { as[node * 4 + hh] = ps[n]; ad[node * 4 + hh] = pd[n]; }
        }
    }
}

// ================================================================ layer-1 gather: 32-edge batches (16 uint2 loads in flight)
// w-lanes: j=lane>>2 (edge 0..15 within half-batch), h4=lane&3. row-lanes: half=lane>>5, d5=lane&31, head=d5>>3
__global__ __launch_bounds__(256) void k_gather1(const int* __restrict__ esrc,
                                                 const int* __restrict__ rowptr,
                                                 const unsigned int* __restrict__ h1,   // [N][64] bf16x2
                                                 const float* __restrict__ as,          // [N][4]
                                                 const float* __restrict__ ad,          // [N][4]
                                                 const float* __restrict__ b1,
                                                 unsigned int* __restrict__ out1) {     // [N][64] bf16x2
    int t = threadIdx.x;
    int node = blockIdx.x * 4 + (t >> 6);
    int lane = t & 63;
    int half = lane >> 5, d5 = lane & 31;
    int head = d5 >> 3;
    int j = lane >> 2, h4 = lane & 3;
    int beg = rowptr[node], end = rowptr[node + 1];
    float ad_w = ad[node * 4 + h4];
    float a0 = 0.f, a1 = 0.f, a2 = 0.f, a3 = 0.f, sw = 0.f;
    int ids0 = esrc[beg + j];            // esrc padded (64): safe unguarded
    int ids1 = esrc[beg + 16 + j];
    for (int k = beg; k < end; k += 32) {
        float asv0 = as[ids0 * 4 + h4];  // issue first: overlap row loads
        float asv1 = as[ids1 * 4 + h4];
        uint2 u[16];
        #pragma unroll
        for (int i = 0; i < 8; i++) {    // 16 rows in flight before any consumption
            int sa = __shfl(ids0, 8 * i, 64);
            int sb = __shfl(ids0, 8 * i + 4, 64);
            u[i] = *(const uint2*)(h1 + (size_t)(half ? sb : sa) * 64 + 2 * d5);
        }
        #pragma unroll
        for (int i = 0; i < 8; i++) {
            int sa = __shfl(ids1, 8 * i, 64);
            int sb = __shfl(ids1, 8 * i + 4, 64);
            u[8 + i] = *(const uint2*)(h1 + (size_t)(half ? sb : sa) * 64 + 2 * d5);
        }
        int ids0n = esrc[k + 32 + j];    // prefetch next 32-edge batch ids
        int ids1n = esrc[k + 48 + j];
        float wm0 = edge_w(asv0, ad_w);
        if (k + j >= end) wm0 = 0.f;     // tail masking at source lane
        float wm1 = edge_w(asv1, ad_w);
        if (k + 16 + j >= end) wm1 = 0.f;
        #pragma unroll
        for (int i = 0; i < 8; i++) {
            float wi = __shfl(wm0, 8 * i + 4 * half + head, 64);
            a0 += bf_lo(u[i].x) * wi; a1 += bf_hi(u[i].x) * wi;
            a2 += bf_lo(u[i].y) * wi; a3 += bf_hi(u[i].y) * wi;
            sw += wi;
        }
        #pragma unroll
        for (int i = 0; i < 8; i++) {
            float wi = __shfl(wm1, 8 * i + 4 * half + head, 64);
            a0 += bf_lo(u[8 + i].x) * wi; a1 += bf_hi(u[8 + i].x) * wi;
            a2 += bf_lo(u[8 + i].y) * wi; a3 += bf_hi(u[8 + i].y) * wi;
            sw += wi;
        }
        ids0 = ids0n; ids1 = ids1n;
    }
    // combine edge-parity halves (lane and lane^32 hold same channels)
    a0 += __shfl_xor(a0, 32, 64);
    a1 += __shfl_xor(a1, 32, 64);
    a2 += __shfl_xor(a2, 32, 64);
    a3 += __shfl_xor(a3, 32, 64);
    sw += __shfl_xor(sw, 32, 64);
    float rs = 1.0f / (sw + 1e-16f);
    float4 bv = *(const float4*)(b1 + 4 * d5);
    float v0 = a0 * rs + bv.x;
    float v1 = a1 * rs + bv.y;
    float v2 = a2 * rs + bv.z;
    float v3 = a3 * rs + bv.w;
    v0 = (v0 > 0.f) ? v0 : (__expf(v0) - 1.0f);   // ELU
    v1 = (v1 > 0.f) ? v1 : (__expf(v1) - 1.0f);
    v2 = (v2 > 0.f) ? v2 : (__expf(v2) - 1.0f);
    v3 = (v3 > 0.f) ? v3 : (__expf(v3) - 1.0f);
    if (half == 0) {
        uint2 o;
        o.x = ((unsigned int)f2bf(v1) << 16) | (unsigned int)f2bf(v0);
        o.y = ((unsigned int)f2bf(v3) << 16) | (unsigned int)f2bf(v2);
        *(uint2*)(out1 + (size_t)node * 64 + 2 * d5) = o;
    }
}

// ================================================================ layer-2 gather: 32-edge batches, dword loads + mean + log_softmax
__global__ __launch_bounds__(256) void k_gather2(const int* __restrict__ esrc,
                                                 const int* __restrict__ rowptr,
                                                 const unsigned int* __restrict__ h2,   // [N][32] dwords (bf16x2)
                                                 const float* __restrict__ as,          // [N][4]
                                                 const float* __restrict__ ad,          // [N][4]
                                                 const float* __restrict__ b2,
                                                 float* __restrict__ out) {
    int t = threadIdx.x;
    int node = blockIdx.x * 4 + (t >> 6);
    int lane = t & 63;
    int half = lane >> 5, d5 = lane & 31;
    int head = d5 >> 3;
    int j = lane >> 2, h4 = lane & 3;
    int beg = rowptr[node], end = rowptr[node + 1];
    float ad_w = ad[node * 4 + h4];
    float a0 = 0.f, a1 = 0.f, sw = 0.f;
    int ids0 = esrc[beg + j];
    int ids1 = esrc[beg + 16 + j];
    for (int k = beg; k < end; k += 32) {
        float asv0 = as[ids0 * 4 + h4];
        float asv1 = as[ids1 * 4 + h4];
        unsigned int u[16];
        #pragma unroll
        for (int i = 0; i < 8; i++) {
            int sa = __shfl(ids0, 8 * i, 64);
            int sb = __shfl(ids0, 8 * i + 4, 64);
            u[i] = h2[(size_t)(half ? sb : sa) * 32 + d5];
        }
        #pragma unroll
        for (int i = 0; i < 8; i++) {
            int sa = __shfl(ids1, 8 * i, 64);
            int sb = __shfl(ids1, 8 * i + 4, 64);
            u[8 + i] = h2[(size_t)(half ? sb : sa) * 32 + d5];
        }
        int ids0n = esrc[k + 32 + j];
        int ids1n = esrc[k + 48 + j];
        float wm0 = edge_w(asv0, ad_w);
        if (k + j >= end) wm0 = 0.f;
        float wm1 = edge_w(asv1, ad_w);
        if (k + 16 + j >= end) wm1 = 0.f;
        #pragma unroll
        for (int i = 0; i < 8; i++) {
            float wi = __shfl(wm0, 8 * i + 4 * half + head, 64);
            a0 += bf_lo(u[i]) * wi;
            a1 += bf_hi(u[i]) * wi;
            sw += wi;
        }
        #pragma unroll
        for (int i = 0; i < 8; i++) {
            float wi = __shfl(wm1, 8 * i + 4 * half + head, 64);
            a0 += bf_lo(u[8 + i]) * wi;
            a1 += bf_hi(u[8 + i]) * wi;
            sw += wi;
        }
        ids0 = ids0n; ids1 = ids1n;
    }
    a0 += __shfl_xor(a0, 32, 64);
    a1 += __shfl_xor(a1, 32, 64);
    sw += __shfl_xor(sw, 32, 64);
    float rs = 1.0f / (sw + 1e-16f);
    float v0 = a0 * rs, v1 = a1 * rs;
    // mean over 4 heads: lanes d5, d5^8, d5^16 hold same classes, different heads
    v0 += __shfl_xor(v0, 8, 64);  v0 += __shfl_xor(v0, 16, 64);
    v1 += __shfl_xor(v1, 8, 64);  v1 += __shfl_xor(v1, 16, 64);
    int c0 = 2 * (d5 & 7);
    v0 = v0 * 0.25f + b2[c0];
    v1 = v1 * 0.25f + b2[c0 + 1];
    // log_softmax over 16 classes: 8 lanes x 2 classes each
    float m = fmaxf(v0, v1);
    #pragma unroll
    for (int mask = 1; mask < 8; mask <<= 1) m = fmaxf(m, __shfl_xor(m, mask, 64));
    float se = __expf(v0 - m) + __expf(v1 - m);
    #pragma unroll
    for (int mask = 1; mask < 8; mask <<= 1) se += __shfl_xor(se, mask, 64);
    float ls = __logf(se);
    if (half == 0 && d5 < 8)
        *(float2*)(out + (size_t)node * 16 + c0) = make_float2((v0 - m) - ls, (v1 - m) - ls);
}

// ================================================================ host
extern "C" void kernel_launch(void* const* d_in, const int* in_sizes, int n_in,
                              void* d_out, int out_size, void* d_ws, size_t ws_size,
                              hipStream_t stream) {
    const float* x      = (const float*)d_in[0];
    const int*   ei     = (const int*)d_in[1];
    const float* Wemb   = (const float*)d_in[2];
    const float* bemb   = (const float*)d_in[3];
    const float* W1     = (const float*)d_in[4];
    const float* a_src1 = (const float*)d_in[5];
    const float* a_dst1 = (const float*)d_in[6];
    const float* b1     = (const float*)d_in[7];
    const float* W2     = (const float*)d_in[8];
    const float* a_src2 = (const float*)d_in[9];
    const float* a_dst2 = (const float*)d_in[10];
    const float* b2     = (const float*)d_in[11];
    float* out = (float*)d_out;

    char* ws = (char*)d_ws;
    size_t off = 0;
    auto alloc = [&](size_t bytes) { char* p = ws + off; off += (bytes + 255) & ~size_t(255); return p; };
    unsigned short* h1b   = (unsigned short*)alloc((size_t)N_NODES * 128 * 2);  // h2b [N][64] overlays front
    unsigned int*   out1b = (unsigned int*)alloc((size_t)N_NODES * 64 * 4);     // [N][64] bf16x2
    float*        h0    = (float*)alloc((size_t)N_NODES * HID * 4);
    int*          esrc  = (int*)alloc((size_t)N_EDGES * 4 + 256);               // +64 pad ints
    unsigned int* pairs = (unsigned int*)alloc((size_t)NBKT * CAP * 4);
    float* as     = (float*)alloc((size_t)N_NODES * 4 * 4);   // [N][4]
    float* ad     = (float*)alloc((size_t)N_NODES * 4 * 4);   // [N][4]
    int*   rowptr = (int*)alloc((size_t)(N_NODES + 1) * 4);
    int*   gcnt   = (int*)alloc((size_t)NBKT * 4);
    unsigned short* h2b = h1b;     // h1b dead after gather1

    const int GB = N_NODES / 4;    // 12500

    hipMemsetAsync(gcnt, 0, (size_t)NBKT * 4, stream);
    k_F1<<<NB64 + NBKT, 256, 0, stream>>>(x, Wemb, bemb, h0, ei, gcnt, pairs, esrc);
    k_F2<<<NB64 + NBKT, 256, 0, stream>>>(h0, W1, a_src1, a_dst1, h1b, as, ad,
                                          pairs, gcnt, rowptr, esrc);
    k_gather1<<<GB, 256, 0, stream>>>(esrc, rowptr, (const unsigned int*)h1b, as, ad, b1, out1b);
    k_h2f<<<NB64, 256, 0, stream>>>(out1b, W2, a_src2, a_dst2, h2b, as, ad);
    k_gather2<<<GB, 256, 0, stream>>>(esrc, rowptr, (const unsigned int*)h2b, as, ad, b2, out);
}